// Round 9
// baseline (550.805 us; speedup 1.0000x reference)
//
#include <hip/hip_runtime.h>

#define B_DIM 32
#define C_DIM 256
#define H_DIM 128
#define W_DIM 256
#define ATT_DIM 256
#define DELAY 768         // context trails pool by 3 batches (~100 MB L3 window)

#define ST(p, v) __hip_atomic_store((p), (v), __ATOMIC_RELAXED, __HIP_MEMORY_SCOPE_AGENT)
#define LD(p)    __hip_atomic_load((p), __ATOMIC_RELAXED, __HIP_MEMORY_SCOPE_AGENT)

typedef float f4 __attribute__((ext_vector_type(4)));

union Smem {
  struct { float res[H_DIM]; } a;
  struct { float n0[H_DIM], n1[H_DIM], ws4[2][4], cw[480]; } nc;
  struct { float At[C_DIM][12]; float Ct[16][9]; float red[8][ATT_DIM]; } b;
  struct { float al[H_DIM], at[H_DIM]; float4 part[4][64]; } c;
};

// flags: [0..31] pool_done[b] (==256), [32..63] align_done[b] (==16), [64] small_done (==64)
__global__ __launch_bounds__(256) void pipe4(
    const float* __restrict__ feat, const float* __restrict__ w_width,
    const float* __restrict__ b_width,
    const float* __restrict__ prev, const float* __restrict__ cov,
    const float* __restrict__ conv_w, const float* __restrict__ conv_b,
    const float* __restrict__ hidden, const float* __restrict__ w_hid,
    const float* __restrict__ b_hid, const float* __restrict__ b_enc,
    const float* __restrict__ b_cb, const float* __restrict__ w_enc,
    const float* __restrict__ w_cb, const float* __restrict__ w_align,
    const float* __restrict__ b_align,
    float* __restrict__ hf, float* __restrict__ convT,
    float* __restrict__ hsum, float* __restrict__ align_buf,
    int* __restrict__ flags,
    float* __restrict__ attn_out, float* __restrict__ ctx)
{
  __shared__ Smem sm;
  const int tid = threadIdx.x;
  const int i = blockIdx.x;

  if (i < B_DIM) {
    // ======== small job 1: InstanceNorm + Conv1d(2->16,k15,p7), b = i ======
    const int b = i;
    for (int j = tid; j < 480; j += 256) sm.nc.cw[j] = conv_w[j];
    const int wv2 = tid >> 6;
    float x0 = 0.f, x1 = 0.f;
    if (tid < 128) {
      x0 = prev[b * H_DIM + tid];
      x1 = cov[b * H_DIM + tid];
      x1 = fminf(fmaxf(x1, 0.0f), 1.0f);
      float s0 = x0, q0 = x0 * x0, s1 = x1, q1 = x1 * x1;
#pragma unroll
      for (int off = 32; off >= 1; off >>= 1) {
        s0 += __shfl_xor(s0, off); q0 += __shfl_xor(q0, off);
        s1 += __shfl_xor(s1, off); q1 += __shfl_xor(q1, off);
      }
      if ((tid & 63) == 0) {
        sm.nc.ws4[wv2][0] = s0; sm.nc.ws4[wv2][1] = q0;
        sm.nc.ws4[wv2][2] = s1; sm.nc.ws4[wv2][3] = q1;
      }
    }
    __syncthreads();
    if (tid < 128) {
      float S0 = sm.nc.ws4[0][0] + sm.nc.ws4[1][0], Q0 = sm.nc.ws4[0][1] + sm.nc.ws4[1][1];
      float S1 = sm.nc.ws4[0][2] + sm.nc.ws4[1][2], Q1 = sm.nc.ws4[0][3] + sm.nc.ws4[1][3];
      const float rH = 1.0f / H_DIM;
      float mu0 = S0 * rH, mu1 = S1 * rH;
      float inv0 = 1.0f / sqrtf(Q0 * rH - mu0 * mu0 + 1e-5f);
      float inv1 = 1.0f / sqrtf(Q1 * rH - mu1 * mu1 + 1e-5f);
      sm.nc.n0[tid] = (x0 - mu0) * inv0;
      sm.nc.n1[tid] = (x1 - mu1) * inv1;
    }
    __syncthreads();
    if (tid < 128) {
      float o[16];
#pragma unroll
      for (int k = 0; k < 16; k++) o[k] = conv_b[k];
#pragma unroll
      for (int j = 0; j < 15; j++) {
        int hh = tid - 7 + j;
        if (hh >= 0 && hh < H_DIM) {
          float f0 = sm.nc.n0[hh], f1 = sm.nc.n1[hh];
#pragma unroll
          for (int k = 0; k < 16; k++)
            o[k] += f0 * sm.nc.cw[k * 30 + j] + f1 * sm.nc.cw[k * 30 + 15 + j];
        }
      }
      float* outp = convT + ((size_t)(b * H_DIM + tid)) * 16;
#pragma unroll
      for (int k = 0; k < 16; k++) ST(&outp[k], o[k]);
    }
    __syncthreads();   // drains vmcnt(0): sc1 stores at coherent point
    if (tid == 0)
      __hip_atomic_fetch_add(&flags[64], 1, __ATOMIC_RELAXED, __HIP_MEMORY_SCOPE_AGENT);
    return;
  }
  if (i < 2 * B_DIM) {
    // ======== small job 2: hsum[b,a] = hidden@w_hid + biases ===============
    const int b = i - B_DIM;
    const int a = tid;
    float acc = b_hid[a] + b_enc[a] + b_cb[a];
    const float* hb = hidden + b * 256;
#pragma unroll 4
    for (int d = 0; d < 256; d++) acc += hb[d] * w_hid[d * ATT_DIM + a];
    ST(&hsum[b * ATT_DIM + a], acc);
    __syncthreads();
    if (tid == 0)
      __hip_atomic_fetch_add(&flags[64], 1, __ATOMIC_RELAXED, __HIP_MEMORY_SCOPE_AGENT);
    return;
  }

  int gemmB = -1, gemmChunk = 0, ctxS = -1;

  if (i < 64 + 8192) {
    // ================= Phase 1: pool+width for slice s (NO dependency) =====
    const int s = i - 64;                 // slice = b*C + c
    {
      const int lane = tid & 63, w = tid >> 6;
      const int half = lane >> 5;
      const int m = lane & 31;
      const float wv = w_width[m];
      const float bw = b_width[0];
      const float* base = feat + (size_t)s * (H_DIM * W_DIM) + m * 8;
#pragma unroll 4
      for (int it = 0; it < 16; it++) {
        const int h = w * 32 + it * 2 + half;
        const f4* p = reinterpret_cast<const f4*>(base + (size_t)h * W_DIM);
        f4 a4 = __builtin_nontemporal_load(p);
        f4 b4 = __builtin_nontemporal_load(p + 1);
        float mx = fmaxf(fmaxf(fmaxf(a4.x, a4.y), fmaxf(a4.z, a4.w)),
                         fmaxf(fmaxf(b4.x, b4.y), fmaxf(b4.z, b4.w)));
        float contrib = mx * wv;
#pragma unroll
        for (int off = 1; off <= 16; off <<= 1) contrib += __shfl_xor(contrib, off);
        if (m == 0) sm.a.res[h] = contrib + bw;
      }
      __syncthreads();
      if (tid < H_DIM) ST(&hf[(size_t)s * H_DIM + tid], sm.a.res[tid]);
      __syncthreads();   // drain sc1 stores
      if (tid == 0)
        __hip_atomic_fetch_add(&flags[s >> 8], 1, __ATOMIC_RELAXED, __HIP_MEMORY_SCOPE_AGENT);
    }
    if ((s & 255) < 16 && s >= 512) { gemmB = (s >> 8) - 2; gemmChunk = s & 15; }
    if (s >= DELAY) ctxS = s - DELAY;
  } else {
    // ================= tail blocks: gemm for b=30/31 + last 3 batches' ctx =
    const int k = i - (64 + 8192);
    if (k < 16)      { gemmB = 30; gemmChunk = k; }
    else if (k < 32) { gemmB = 31; gemmChunk = k - 16; }
    ctxS = 8192 - DELAY + k;
  }

  if (gemmB >= 0) {
    // ================= Phase 2: GEMM + tanh + align (8 rows) ===============
    const int b = gemmB;
    if (tid == 0) {
      while (LD(&flags[b]) < 256) __builtin_amdgcn_s_sleep(8);
      while (LD(&flags[64]) < 64) __builtin_amdgcn_s_sleep(8);
    }
    __syncthreads();
    const int h0 = gemmChunk * 8;
    const int m0 = b * H_DIM + h0;
    const float* hp = hf + ((size_t)(b * C_DIM + tid)) * H_DIM + h0;
#pragma unroll
    for (int j = 0; j < 8; j++) sm.b.At[tid][j] = LD(&hp[j]);   // sc1 loads
    if (tid < 128) {
      int mm = tid >> 4, kk = tid & 15;
      sm.b.Ct[kk][mm] = LD(&convT[(size_t)(b * H_DIM + h0) * 16 + tid]);
    }
    __syncthreads();
    float acc[8];
#pragma unroll
    for (int mm = 0; mm < 8; mm++) acc[mm] = 0.0f;
    const float* wep = w_enc + tid;
#pragma unroll 4
    for (int k = 0; k < C_DIM; k++) {
      float bv = wep[k * ATT_DIM];
      const float4 a0 = *reinterpret_cast<const float4*>(&sm.b.At[k][0]);
      const float4 a1 = *reinterpret_cast<const float4*>(&sm.b.At[k][4]);
      acc[0] += a0.x * bv; acc[1] += a0.y * bv; acc[2] += a0.z * bv; acc[3] += a0.w * bv;
      acc[4] += a1.x * bv; acc[5] += a1.y * bv; acc[6] += a1.z * bv; acc[7] += a1.w * bv;
    }
#pragma unroll
    for (int k = 0; k < 16; k++) {
      float bv = w_cb[k * ATT_DIM + tid];
#pragma unroll
      for (int mm = 0; mm < 8; mm++) acc[mm] += sm.b.Ct[k][mm] * bv;
    }
    const float hs = LD(&hsum[b * ATT_DIM + tid]);
    const float wa = w_align[tid];
#pragma unroll
    for (int mm = 0; mm < 8; mm++)
      sm.b.red[mm][tid] = tanhf(acc[mm] + hs) * wa;
    __syncthreads();
    const int lane = tid & 63, wid = tid >> 6;
    const float ba = b_align[0];
    for (int mm = wid; mm < 8; mm += 4) {
      float ss = sm.b.red[mm][lane] + sm.b.red[mm][lane + 64] +
                 sm.b.red[mm][lane + 128] + sm.b.red[mm][lane + 192];
#pragma unroll
      for (int off = 32; off >= 1; off >>= 1) ss += __shfl_xor(ss, off);
      if (lane == 0) ST(&align_buf[m0 + mm], ss + ba);
    }
    __syncthreads();   // drain sc1 stores
    if (tid == 0)
      __hip_atomic_fetch_add(&flags[32 + b], 1, __ATOMIC_RELAXED, __HIP_MEMORY_SCOPE_AGENT);
  }

  if (ctxS >= 0) {
    // ================= Phase 3: softmax + context for slice ctxS ===========
    const int bc = ctxS;
    const int b = bc >> 8, c = bc & 255;
    if (tid == 0) {
      while (LD(&flags[32 + b]) < 16) __builtin_amdgcn_s_sleep(8);
    }
    __syncthreads();
    if (tid < H_DIM) sm.c.al[tid] = LD(&align_buf[(b << 7) + tid]);   // sc1
    __syncthreads();
    if (tid < 64) {
      float a0 = sm.c.al[tid], a1 = sm.c.al[tid + 64];
      float mx = fmaxf(a0, a1);
#pragma unroll
      for (int off = 32; off >= 1; off >>= 1) mx = fmaxf(mx, __shfl_xor(mx, off));
      float e0 = expf(a0 - mx), e1 = expf(a1 - mx);
      float ss = e0 + e1;
#pragma unroll
      for (int off = 32; off >= 1; off >>= 1) ss += __shfl_xor(ss, off);
      float inv = 1.0f / ss;
      sm.c.at[tid] = e0 * inv;
      sm.c.at[tid + 64] = e1 * inv;
    }
    __syncthreads();
    if (c == 0 && tid < H_DIM) attn_out[(b << 7) + tid] = sm.c.at[tid];
    const int g = tid >> 6, lane = tid & 63;
    const float* base = feat + (size_t)bc * (H_DIM * W_DIM) + lane * 4;
    float4 acc0 = make_float4(0.f, 0.f, 0.f, 0.f);
    float4 acc1 = make_float4(0.f, 0.f, 0.f, 0.f);
#pragma unroll 2
    for (int h = g; h < H_DIM; h += 8) {
      f4 v0 = __builtin_nontemporal_load(
          reinterpret_cast<const f4*>(base + (size_t)h * W_DIM));
      f4 v1 = __builtin_nontemporal_load(
          reinterpret_cast<const f4*>(base + (size_t)(h + 4) * W_DIM));
      float a0 = sm.c.at[h], a1 = sm.c.at[h + 4];
      acc0.x += v0.x * a0; acc0.y += v0.y * a0; acc0.z += v0.z * a0; acc0.w += v0.w * a0;
      acc1.x += v1.x * a1; acc1.y += v1.y * a1; acc1.z += v1.z * a1; acc1.w += v1.w * a1;
    }
    float4 acc;
    acc.x = acc0.x + acc1.x; acc.y = acc0.y + acc1.y;
    acc.z = acc0.z + acc1.z; acc.w = acc0.w + acc1.w;
    sm.c.part[g][lane] = acc;
    __syncthreads();
    if (tid < 64) {
      float4 p0 = sm.c.part[0][tid], p1 = sm.c.part[1][tid];
      float4 p2 = sm.c.part[2][tid], p3 = sm.c.part[3][tid];
      float4 o;
      o.x = p0.x + p1.x + p2.x + p3.x;
      o.y = p0.y + p1.y + p2.y + p3.y;
      o.z = p0.z + p1.z + p2.z + p3.z;
      o.w = p0.w + p1.w + p2.w + p3.w;
      *reinterpret_cast<float4*>(ctx + (size_t)bc * W_DIM + tid * 4) = o;
    }
  }
}

// ---------------------------------------------------------------------------
extern "C" void kernel_launch(void* const* d_in, const int* in_sizes, int n_in,
                              void* d_out, int out_size, void* d_ws, size_t ws_size,
                              hipStream_t stream)
{
  const float* feat    = (const float*)d_in[0];
  const float* prev    = (const float*)d_in[1];
  const float* cov     = (const float*)d_in[2];
  const float* hidden  = (const float*)d_in[3];
  const float* w_width = (const float*)d_in[4];
  const float* b_width = (const float*)d_in[5];
  const float* w_enc   = (const float*)d_in[6];
  const float* b_enc   = (const float*)d_in[7];
  const float* conv_w  = (const float*)d_in[8];
  const float* conv_b  = (const float*)d_in[9];
  const float* w_cb    = (const float*)d_in[10];
  const float* b_cb    = (const float*)d_in[11];
  const float* w_hid   = (const float*)d_in[12];
  const float* b_hid   = (const float*)d_in[13];
  const float* w_align = (const float*)d_in[14];
  const float* b_align = (const float*)d_in[15];

  float* ctx_out  = (float*)d_out;                                   // (B,C,W)
  float* attn_out = (float*)d_out + (size_t)B_DIM * C_DIM * W_DIM;   // (B,H)

  float* ws       = (float*)d_ws;
  float* hf       = ws;                 // (B,C,H)  = 1048576 floats
  float* convT    = hf + 1048576;       // (B,H,16) = 65536
  float* hsum     = convT + 65536;      // (B,ATT)  = 8192
  float* align_b  = hsum + 8192;        // (B,H)    = 4096
  int*   flags    = (int*)(align_b + 4096);  // 65 ints

  hipMemsetAsync(flags, 0, 512, stream);
  pipe4<<<dim3(64 + 8192 + DELAY), dim3(256), 0, stream>>>(
      feat, w_width, b_width, prev, cov, conv_w, conv_b,
      hidden, w_hid, b_hid, b_enc, b_cb, w_enc, w_cb, w_align, b_align,
      hf, convT, hsum, align_b, flags, attn_out, ctx_out);
}

// Round 10
// 433.249 us; speedup vs baseline: 1.2713x; 1.2713x over previous
//
#include <hip/hip_runtime.h>

#define B_DIM 32
#define C_DIM 256
#define H_DIM 128
#define W_DIM 256
#define ATT_DIM 256

#define ST(p, v) __hip_atomic_store((p), (v), __ATOMIC_RELAXED, __HIP_MEMORY_SCOPE_AGENT)
#define LD(p)    __hip_atomic_load((p), __ATOMIC_RELAXED, __HIP_MEMORY_SCOPE_AGENT)

union Smem {
  struct { float res[H_DIM]; } a;
  struct { float n0[H_DIM], n1[H_DIM], ws4[2][4], cw[480]; } nc;
  struct { float At[C_DIM][12]; float Ct[16][9]; float red[8][ATT_DIM]; } b;
};

// flags: [0..31] pool_done[b] (==256), [64] small_done (==64)
// Dispatch 1: blocks 0..31 norm+conv | 32..63 hsum | 64..8255 pool | 8256..8767 gemm
__global__ __launch_bounds__(256) void ka2(
    const float* __restrict__ feat, const float* __restrict__ w_width,
    const float* __restrict__ b_width,
    const float* __restrict__ prev, const float* __restrict__ cov,
    const float* __restrict__ conv_w, const float* __restrict__ conv_b,
    const float* __restrict__ hidden, const float* __restrict__ w_hid,
    const float* __restrict__ b_hid, const float* __restrict__ b_enc,
    const float* __restrict__ b_cb, const float* __restrict__ w_enc,
    const float* __restrict__ w_cb, const float* __restrict__ w_align,
    const float* __restrict__ b_align,
    float* __restrict__ hf, float* __restrict__ convT,
    float* __restrict__ hsum, float* __restrict__ align_buf,
    int* __restrict__ flags)
{
  __shared__ Smem sm;
  const int tid = threadIdx.x;
  const int i = blockIdx.x;

  if (i < B_DIM) {
    // ======== InstanceNorm1d(2ch over H) + Conv1d(2->16,k15,p7), b = i =====
    const int b = i;
    for (int j = tid; j < 480; j += 256) sm.nc.cw[j] = conv_w[j];
    const int wv2 = tid >> 6;
    float x0 = 0.f, x1 = 0.f;
    if (tid < 128) {
      x0 = prev[b * H_DIM + tid];
      x1 = cov[b * H_DIM + tid];
      x1 = fminf(fmaxf(x1, 0.0f), 1.0f);
      float s0 = x0, q0 = x0 * x0, s1 = x1, q1 = x1 * x1;
#pragma unroll
      for (int off = 32; off >= 1; off >>= 1) {
        s0 += __shfl_xor(s0, off); q0 += __shfl_xor(q0, off);
        s1 += __shfl_xor(s1, off); q1 += __shfl_xor(q1, off);
      }
      if ((tid & 63) == 0) {
        sm.nc.ws4[wv2][0] = s0; sm.nc.ws4[wv2][1] = q0;
        sm.nc.ws4[wv2][2] = s1; sm.nc.ws4[wv2][3] = q1;
      }
    }
    __syncthreads();
    if (tid < 128) {
      float S0 = sm.nc.ws4[0][0] + sm.nc.ws4[1][0], Q0 = sm.nc.ws4[0][1] + sm.nc.ws4[1][1];
      float S1 = sm.nc.ws4[0][2] + sm.nc.ws4[1][2], Q1 = sm.nc.ws4[0][3] + sm.nc.ws4[1][3];
      const float rH = 1.0f / H_DIM;
      float mu0 = S0 * rH, mu1 = S1 * rH;
      float inv0 = 1.0f / sqrtf(Q0 * rH - mu0 * mu0 + 1e-5f);
      float inv1 = 1.0f / sqrtf(Q1 * rH - mu1 * mu1 + 1e-5f);
      sm.nc.n0[tid] = (x0 - mu0) * inv0;
      sm.nc.n1[tid] = (x1 - mu1) * inv1;
    }
    __syncthreads();
    if (tid < 128) {
      float o[16];
#pragma unroll
      for (int k = 0; k < 16; k++) o[k] = conv_b[k];
#pragma unroll
      for (int j = 0; j < 15; j++) {
        int hh = tid - 7 + j;
        if (hh >= 0 && hh < H_DIM) {
          float f0 = sm.nc.n0[hh], f1 = sm.nc.n1[hh];
#pragma unroll
          for (int k = 0; k < 16; k++)
            o[k] += f0 * sm.nc.cw[k * 30 + j] + f1 * sm.nc.cw[k * 30 + 15 + j];
        }
      }
      float* outp = convT + ((size_t)(b * H_DIM + tid)) * 16;
#pragma unroll
      for (int k = 0; k < 16; k++) ST(&outp[k], o[k]);
    }
    __syncthreads();   // drains vmcnt: sc1 stores at coherent point
    if (tid == 0)
      __hip_atomic_fetch_add(&flags[64], 1, __ATOMIC_RELAXED, __HIP_MEMORY_SCOPE_AGENT);
    return;
  }
  if (i < 2 * B_DIM) {
    // ======== hsum[b,a] = hidden[b,:] @ w_hid[:,a] + b_hid + b_enc + b_cb ==
    const int b = i - B_DIM;
    const int a = tid;
    float acc = b_hid[a] + b_enc[a] + b_cb[a];
    const float* hb = hidden + b * 256;
#pragma unroll 4
    for (int d = 0; d < 256; d++) acc += hb[d] * w_hid[d * ATT_DIM + a];
    ST(&hsum[b * ATT_DIM + a], acc);
    __syncthreads();
    if (tid == 0)
      __hip_atomic_fetch_add(&flags[64], 1, __ATOMIC_RELAXED, __HIP_MEMORY_SCOPE_AGENT);
    return;
  }

  if (i < 64 + 8192) {
    // ======== pool+width for slice s -> hf (B,C,H) ==========================
    const int s = i - 64;                 // slice = b*C + c
    const int lane = tid & 63, w = tid >> 6;
    const int half = lane >> 5;
    const int m = lane & 31;
    const float wv = w_width[m];
    const float bw = b_width[0];
    const float* base = feat + (size_t)s * (H_DIM * W_DIM) + m * 8;
#pragma unroll 4
    for (int it = 0; it < 16; it++) {
      const int h = w * 32 + it * 2 + half;
      const float4* p = reinterpret_cast<const float4*>(base + (size_t)h * W_DIM);
      float4 a4 = p[0], b4 = p[1];
      float mx = fmaxf(fmaxf(fmaxf(a4.x, a4.y), fmaxf(a4.z, a4.w)),
                       fmaxf(fmaxf(b4.x, b4.y), fmaxf(b4.z, b4.w)));
      float contrib = mx * wv;
#pragma unroll
      for (int off = 1; off <= 16; off <<= 1) contrib += __shfl_xor(contrib, off);
      if (m == 0) sm.a.res[h] = contrib + bw;
    }
    __syncthreads();
    if (tid < H_DIM) ST(&hf[(size_t)s * H_DIM + tid], sm.a.res[tid]);
    __syncthreads();   // drain sc1 stores
    if (tid == 0)
      __hip_atomic_fetch_add(&flags[s >> 8], 1, __ATOMIC_RELAXED, __HIP_MEMORY_SCOPE_AGENT);
    return;
  }

  // ======== gemm tail blocks: 512 blocks, 8 rows each =======================
  {
    const int k0 = i - (64 + 8192);
    const int b = k0 >> 4;
    const int h0 = (k0 & 15) * 8;
    if (tid == 0) {
      while (LD(&flags[b]) < 256) __builtin_amdgcn_s_sleep(8);
      while (LD(&flags[64]) < 64) __builtin_amdgcn_s_sleep(8);
    }
    __syncthreads();
    const int m0 = b * H_DIM + h0;
    const float* hp = hf + ((size_t)(b * C_DIM + tid)) * H_DIM + h0;
#pragma unroll
    for (int j = 0; j < 8; j++) sm.b.At[tid][j] = LD(&hp[j]);   // sc1 loads
    if (tid < 128) {
      int mm = tid >> 4, kk = tid & 15;
      sm.b.Ct[kk][mm] = LD(&convT[(size_t)(b * H_DIM + h0) * 16 + tid]);
    }
    __syncthreads();
    float acc[8];
#pragma unroll
    for (int mm = 0; mm < 8; mm++) acc[mm] = 0.0f;
    const float* wep = w_enc + tid;
#pragma unroll 4
    for (int k = 0; k < C_DIM; k++) {
      float bv = wep[k * ATT_DIM];
      const float4 a0 = *reinterpret_cast<const float4*>(&sm.b.At[k][0]);
      const float4 a1 = *reinterpret_cast<const float4*>(&sm.b.At[k][4]);
      acc[0] += a0.x * bv; acc[1] += a0.y * bv; acc[2] += a0.z * bv; acc[3] += a0.w * bv;
      acc[4] += a1.x * bv; acc[5] += a1.y * bv; acc[6] += a1.z * bv; acc[7] += a1.w * bv;
    }
#pragma unroll
    for (int k = 0; k < 16; k++) {
      float bv = w_cb[k * ATT_DIM + tid];
#pragma unroll
      for (int mm = 0; mm < 8; mm++) acc[mm] += sm.b.Ct[k][mm] * bv;
    }
    const float hs = LD(&hsum[b * ATT_DIM + tid]);
    const float wa = w_align[tid];
#pragma unroll
    for (int mm = 0; mm < 8; mm++)
      sm.b.red[mm][tid] = tanhf(acc[mm] + hs) * wa;
    __syncthreads();
    const int lane = tid & 63, wid = tid >> 6;
    const float ba = b_align[0];
    for (int mm = wid; mm < 8; mm += 4) {
      float ss = sm.b.red[mm][lane] + sm.b.red[mm][lane + 64] +
                 sm.b.red[mm][lane + 128] + sm.b.red[mm][lane + 192];
#pragma unroll
      for (int off = 32; off >= 1; off >>= 1) ss += __shfl_xor(ss, off);
      if (lane == 0) align_buf[m0 + mm] = ss + ba;   // plain: next dispatch reads
    }
  }
}

// ---------------------------------------------------------------------------
// Dispatch 2: in-block softmax over H + context reduce (round-4 proven kernel).
__global__ __launch_bounds__(256) void kc_context(
    const float* __restrict__ feat, const float* __restrict__ align,
    float* __restrict__ attn_out, float* __restrict__ ctx)
{
  const int bc = 8191 - blockIdx.x;   // b*C + c, reversed
  const int b = bc >> 8, c = bc & 255;
  const int tid = threadIdx.x;
  __shared__ float al[H_DIM], at[H_DIM];
  if (tid < H_DIM) al[tid] = align[(b << 7) + tid];
  __syncthreads();
  if (tid < 64) {
    float a0 = al[tid], a1 = al[tid + 64];
    float mx = fmaxf(a0, a1);
#pragma unroll
    for (int off = 32; off >= 1; off >>= 1) mx = fmaxf(mx, __shfl_xor(mx, off));
    float e0 = expf(a0 - mx), e1 = expf(a1 - mx);
    float s = e0 + e1;
#pragma unroll
    for (int off = 32; off >= 1; off >>= 1) s += __shfl_xor(s, off);
    float inv = 1.0f / s;
    at[tid] = e0 * inv;
    at[tid + 64] = e1 * inv;
  }
  __syncthreads();
  if (c == 0 && tid < H_DIM) attn_out[(b << 7) + tid] = at[tid];
  const int g = tid >> 6, lane = tid & 63;
  const float* base = feat + (size_t)bc * H_DIM * W_DIM + lane * 4;
  float4 acc0 = make_float4(0.f, 0.f, 0.f, 0.f);
  float4 acc1 = make_float4(0.f, 0.f, 0.f, 0.f);
#pragma unroll 2
  for (int h = g; h < H_DIM; h += 8) {
    float4 v0 = *reinterpret_cast<const float4*>(base + (size_t)h * W_DIM);
    float4 v1 = *reinterpret_cast<const float4*>(base + (size_t)(h + 4) * W_DIM);
    float a0 = at[h], a1 = at[h + 4];
    acc0.x += v0.x * a0; acc0.y += v0.y * a0; acc0.z += v0.z * a0; acc0.w += v0.w * a0;
    acc1.x += v1.x * a1; acc1.y += v1.y * a1; acc1.z += v1.z * a1; acc1.w += v1.w * a1;
  }
  __shared__ float4 part[4][64];
  float4 acc;
  acc.x = acc0.x + acc1.x; acc.y = acc0.y + acc1.y;
  acc.z = acc0.z + acc1.z; acc.w = acc0.w + acc1.w;
  part[g][lane] = acc;
  __syncthreads();
  if (tid < 64) {
    float4 r0 = part[0][tid], r1 = part[1][tid], r2 = part[2][tid], r3 = part[3][tid];
    float4 o;
    o.x = r0.x + r1.x + r2.x + r3.x;
    o.y = r0.y + r1.y + r2.y + r3.y;
    o.z = r0.z + r1.z + r2.z + r3.z;
    o.w = r0.w + r1.w + r2.w + r3.w;
    *reinterpret_cast<float4*>(ctx + (size_t)bc * W_DIM + tid * 4) = o;
  }
}

// ---------------------------------------------------------------------------
extern "C" void kernel_launch(void* const* d_in, const int* in_sizes, int n_in,
                              void* d_out, int out_size, void* d_ws, size_t ws_size,
                              hipStream_t stream)
{
  const float* feat    = (const float*)d_in[0];
  const float* prev    = (const float*)d_in[1];
  const float* cov     = (const float*)d_in[2];
  const float* hidden  = (const float*)d_in[3];
  const float* w_width = (const float*)d_in[4];
  const float* b_width = (const float*)d_in[5];
  const float* w_enc   = (const float*)d_in[6];
  const float* b_enc   = (const float*)d_in[7];
  const float* conv_w  = (const float*)d_in[8];
  const float* conv_b  = (const float*)d_in[9];
  const float* w_cb    = (const float*)d_in[10];
  const float* b_cb    = (const float*)d_in[11];
  const float* w_hid   = (const float*)d_in[12];
  const float* b_hid   = (const float*)d_in[13];
  const float* w_align = (const float*)d_in[14];
  const float* b_align = (const float*)d_in[15];

  float* ctx_out  = (float*)d_out;                                   // (B,C,W)
  float* attn_out = (float*)d_out + (size_t)B_DIM * C_DIM * W_DIM;   // (B,H)

  float* ws       = (float*)d_ws;
  float* hf       = ws;                 // (B,C,H)  = 1048576 floats
  float* convT    = hf + 1048576;       // (B,H,16) = 65536
  float* hsum     = convT + 65536;      // (B,ATT)  = 8192
  float* align_b  = hsum + 8192;        // (B,H)    = 4096
  int*   flags    = (int*)(align_b + 4096);  // 65 ints

  hipMemsetAsync(flags, 0, 512, stream);
  ka2<<<dim3(64 + 8192 + 512), dim3(256), 0, stream>>>(
      feat, w_width, b_width, prev, cov, conv_w, conv_b,
      hidden, w_hid, b_hid, b_enc, b_cb, w_enc, w_cb, w_align, b_align,
      hf, convT, hsum, align_b, flags);
  kc_context<<<dim3(B_DIM * C_DIM), dim3(256), 0, stream>>>(
      feat, align_b, attn_out, ctx_out);
}